// Round 1
// baseline (318.293 us; speedup 1.0000x reference)
//
#include <hip/hip_runtime.h>
#include <hip/hip_bf16.h>

// ---------------------------------------------------------------------------
// CDAE forward: hidden = tanh(dropout_sparse(A) @ en_emb + user_emb[uids] + off)
//               ratings[n] = dot(hidden[bat_idx[n]], de_emb[bat_items[n]]) + de_bias
//               reg = 0.5*(masked ||en_emb||^2 + ||off||^2 + ||user_emb[uids]||^2
//                          + masked ||de_emb||^2 + masked de_bias^2)
// Dropout mask must replicate jax.random.bernoulli(jax.random.key(42), 0.8, (NNZ,))
// PARTITIONABLE=1 -> modern JAX default (threefry_partitionable): bits[i]=o0^o1 of
//                    block (hi=0, lo=i).  Set to 0 for legacy split-halves mode.
// ---------------------------------------------------------------------------
#define PARTITIONABLE 1

__device__ __forceinline__ unsigned rotl32(unsigned x, int r) {
    return (x << r) | (x >> (32 - r));
}

// JAX threefry2x32 block cipher, key (k0,k1), state (x0,x1) in/out.
__device__ __forceinline__ void threefry2x32(unsigned k0, unsigned k1,
                                             unsigned& x0, unsigned& x1) {
    unsigned ks0 = k0, ks1 = k1, ks2 = k0 ^ k1 ^ 0x1BD11BDAu;
    x0 += ks0; x1 += ks1;
#define TF_R(r) { x0 += x1; x1 = rotl32(x1, r); x1 ^= x0; }
    TF_R(13) TF_R(15) TF_R(26) TF_R(6)   x0 += ks1; x1 += ks2 + 1u;
    TF_R(17) TF_R(29) TF_R(16) TF_R(24)  x0 += ks2; x1 += ks0 + 2u;
    TF_R(13) TF_R(15) TF_R(26) TF_R(6)   x0 += ks0; x1 += ks1 + 3u;
    TF_R(17) TF_R(29) TF_R(16) TF_R(24)  x0 += ks1; x1 += ks2 + 4u;
    TF_R(13) TF_R(15) TF_R(26) TF_R(6)   x0 += ks2; x1 += ks0 + 5u;
#undef TF_R
}

// uniform(key(42))[i] < 0.8f  (exact JAX semantics: f = bitcast((bits>>9)|1.0f) - 1)
__device__ __forceinline__ bool keep_mask(int i, int nnz) {
#if PARTITIONABLE
    unsigned x0 = 0u, x1 = (unsigned)i;          // counts are uint64 iota: hi=0, lo=i
    threefry2x32(0u, 42u, x0, x1);
    unsigned bits = x0 ^ x1;
#else
    int half = nnz >> 1;
    int j = (i < half) ? i : i - half;
    unsigned x0 = (unsigned)j, x1 = (unsigned)(j + half);
    threefry2x32(0u, 42u, x0, x1);
    unsigned bits = (i < half) ? x0 : x1;
#endif
    float u = __uint_as_float((bits >> 9) | 0x3f800000u) - 1.0f;
    return u < 0.8f;
}

// --- item mask: mask[bat_items[n]] = 1 -------------------------------------
__global__ void k_mask(const int* __restrict__ bat_items, unsigned char* __restrict__ mask,
                       int N) {
    int t = blockIdx.x * blockDim.x + threadIdx.x;
    if (t < N) mask[bat_items[t]] = 1;
}

// --- sparse scatter: hidden[row] += 1.25 * en_emb[col]  (one wave per nnz) --
__global__ void k_scatter(const int* __restrict__ sp_row, const int* __restrict__ sp_col,
                          const float* __restrict__ en_emb, float* __restrict__ hidden,
                          int nnz) {
    int t = blockIdx.x * blockDim.x + threadIdx.x;
    int i = t >> 6;            // nnz index (wave-uniform)
    int lane = t & 63;         // feature dim
    if (i >= nnz) return;
    if (!keep_mask(i, nnz)) return;   // wave-uniform branch
    int row = sp_row[i];
    int col = sp_col[i];
    float v = 1.25f * en_emb[(size_t)col * 64 + lane];
    atomicAdd(&hidden[row * 64 + lane], v);
}

// --- hidden = tanh(hidden + user_emb[uids] + en_offset) --------------------
__global__ void k_hfinish(float* __restrict__ hidden, const float* __restrict__ user_emb,
                          const int* __restrict__ user_ids, const float* __restrict__ en_off,
                          int B) {
    int t = blockIdx.x * blockDim.x + threadIdx.x;
    if (t >= B * 64) return;
    int b = t >> 6, d = t & 63;
    int uid = user_ids[b];
    float h = hidden[t] + user_emb[(size_t)uid * 64 + d] + en_off[d];
    hidden[t] = tanhf(h);
}

// --- ratings: 16 lanes per pair, float4 loads, shfl-xor reduce -------------
__global__ void k_ratings(const float* __restrict__ hidden, const float* __restrict__ de_emb,
                          const float* __restrict__ de_bias,
                          const int* __restrict__ bat_idx, const int* __restrict__ bat_items,
                          float* __restrict__ out, int N) {
    int t = blockIdx.x * blockDim.x + threadIdx.x;
    int n = t >> 4;            // pair index (uniform across the 16-lane group)
    int l = t & 15;
    if (n >= N) return;
    int b  = bat_idx[n];
    int it = bat_items[n];
    float4 hv = *reinterpret_cast<const float4*>(hidden + (size_t)b  * 64 + l * 4);
    float4 dv = *reinterpret_cast<const float4*>(de_emb + (size_t)it * 64 + l * 4);
    float s = hv.x * dv.x + hv.y * dv.y + hv.z * dv.z + hv.w * dv.w;
    s += __shfl_xor(s, 1);
    s += __shfl_xor(s, 2);
    s += __shfl_xor(s, 4);
    s += __shfl_xor(s, 8);
    if (l == 0) out[n] = s + de_bias[it];
}

// --- reg part A: masked sum of en^2 + de^2 + de_bias^2 over items ----------
__global__ void k_reg_items(const unsigned char* __restrict__ mask,
                            const float* __restrict__ en_emb, const float* __restrict__ de_emb,
                            const float* __restrict__ de_bias, float* __restrict__ reg,
                            int num_items) {
    int t = blockIdx.x * blockDim.x + threadIdx.x;
    int i = t >> 4, l = t & 15;
    float s = 0.f;
    if (i < num_items && mask[i]) {
        float4 e = *reinterpret_cast<const float4*>(en_emb + (size_t)i * 64 + l * 4);
        float4 d = *reinterpret_cast<const float4*>(de_emb + (size_t)i * 64 + l * 4);
        s = e.x*e.x + e.y*e.y + e.z*e.z + e.w*e.w
          + d.x*d.x + d.y*d.y + d.z*d.z + d.w*d.w;
        if (l == 0) { float bb = de_bias[i]; s += bb * bb; }
    }
    for (int m = 1; m < 64; m <<= 1) s += __shfl_xor(s, m);
    __shared__ float wsum[4];
    if ((threadIdx.x & 63) == 0) wsum[threadIdx.x >> 6] = s;
    __syncthreads();
    if (threadIdx.x == 0)
        atomicAdd(reg, 0.5f * (wsum[0] + wsum[1] + wsum[2] + wsum[3]));
}

// --- reg part B: sum user_emb[uids]^2 (all B rows, dups included) + offset^2
__global__ void k_reg_user(const float* __restrict__ user_emb, const int* __restrict__ user_ids,
                           const float* __restrict__ en_off, float* __restrict__ reg, int B) {
    int t = blockIdx.x * blockDim.x + threadIdx.x;
    int b = t >> 4, l = t & 15;
    float s = 0.f;
    if (b < B) {
        int uid = user_ids[b];
        float4 u = *reinterpret_cast<const float4*>(user_emb + (size_t)uid * 64 + l * 4);
        s = u.x*u.x + u.y*u.y + u.z*u.z + u.w*u.w;
    }
    if (blockIdx.x == 0 && threadIdx.x < 64) {   // en_offset^2, 64 dims
        float o = en_off[threadIdx.x];
        s += o * o;
    }
    for (int m = 1; m < 64; m <<= 1) s += __shfl_xor(s, m);
    __shared__ float wsum[4];
    if ((threadIdx.x & 63) == 0) wsum[threadIdx.x >> 6] = s;
    __syncthreads();
    if (threadIdx.x == 0)
        atomicAdd(reg, 0.5f * (wsum[0] + wsum[1] + wsum[2] + wsum[3]));
}

extern "C" void kernel_launch(void* const* d_in, const int* in_sizes, int n_in,
                              void* d_out, int out_size, void* d_ws, size_t ws_size,
                              hipStream_t stream) {
    const int*   user_ids  = (const int*)  d_in[0];
    const int*   bat_idx   = (const int*)  d_in[1];
    const int*   sp_row    = (const int*)  d_in[2];
    const int*   sp_col    = (const int*)  d_in[3];
    const int*   bat_items = (const int*)  d_in[4];
    const float* en_emb    = (const float*)d_in[5];
    const float* en_off    = (const float*)d_in[6];
    const float* de_emb    = (const float*)d_in[7];
    const float* de_bias   = (const float*)d_in[8];
    const float* user_emb  = (const float*)d_in[9];

    const int B         = in_sizes[0];
    const int N         = in_sizes[1];
    const int NNZ       = in_sizes[2];
    const int NUM_ITEMS = in_sizes[8];

    float* out = (float*)d_out;        // ratings [N]
    float* reg = out + N;              // reg_loss scalar

    float* hidden = (float*)d_ws;                               // B*64 floats = 1 MiB
    unsigned char* mask = (unsigned char*)d_ws + (size_t)B * 64 * 4;  // NUM_ITEMS bytes

    hipMemsetAsync(hidden, 0, (size_t)B * 64 * sizeof(float), stream);
    hipMemsetAsync(mask, 0, (size_t)NUM_ITEMS, stream);
    hipMemsetAsync(reg, 0, sizeof(float), stream);

    k_mask   <<<(N + 255) / 256, 256, 0, stream>>>(bat_items, mask, N);
    k_scatter<<<(NNZ * 64 + 255) / 256, 256, 0, stream>>>(sp_row, sp_col, en_emb, hidden, NNZ);
    k_hfinish<<<(B * 64 + 255) / 256, 256, 0, stream>>>(hidden, user_emb, user_ids, en_off, B);
    k_ratings<<<(int)(((size_t)N * 16 + 255) / 256), 256, 0, stream>>>(
        hidden, de_emb, de_bias, bat_idx, bat_items, out, N);
    k_reg_items<<<(NUM_ITEMS * 16 + 255) / 256, 256, 0, stream>>>(
        mask, en_emb, de_emb, de_bias, reg, NUM_ITEMS);
    k_reg_user<<<(B * 16 + 255) / 256, 256, 0, stream>>>(user_emb, user_ids, en_off, reg, B);
}

// Round 2
// 260.489 us; speedup vs baseline: 1.2219x; 1.2219x over previous
//
#include <hip/hip_runtime.h>
#include <hip/hip_bf16.h>

// ---------------------------------------------------------------------------
// CDAE forward. Round 2: fix atomic-serialization in reg kernels.
// R1 evidence: k_reg_items = 83.7us @ 318 GB/s, 6250 blocks x 1 same-address
// atomicAdd = 13.4ns/atomic serialization. Fix: grid-stride, 256/64 blocks.
// ---------------------------------------------------------------------------
#define PARTITIONABLE 1

__device__ __forceinline__ unsigned rotl32(unsigned x, int r) {
    return (x << r) | (x >> (32 - r));
}

// JAX threefry2x32 block cipher, key (k0,k1), state (x0,x1) in/out.
__device__ __forceinline__ void threefry2x32(unsigned k0, unsigned k1,
                                             unsigned& x0, unsigned& x1) {
    unsigned ks0 = k0, ks1 = k1, ks2 = k0 ^ k1 ^ 0x1BD11BDAu;
    x0 += ks0; x1 += ks1;
#define TF_R(r) { x0 += x1; x1 = rotl32(x1, r); x1 ^= x0; }
    TF_R(13) TF_R(15) TF_R(26) TF_R(6)   x0 += ks1; x1 += ks2 + 1u;
    TF_R(17) TF_R(29) TF_R(16) TF_R(24)  x0 += ks2; x1 += ks0 + 2u;
    TF_R(13) TF_R(15) TF_R(26) TF_R(6)   x0 += ks0; x1 += ks1 + 3u;
    TF_R(17) TF_R(29) TF_R(16) TF_R(24)  x0 += ks1; x1 += ks2 + 4u;
    TF_R(13) TF_R(15) TF_R(26) TF_R(6)   x0 += ks2; x1 += ks0 + 5u;
#undef TF_R
}

// uniform(key(42))[i] < 0.8f  (exact JAX semantics)
__device__ __forceinline__ bool keep_mask(int i, int nnz) {
#if PARTITIONABLE
    unsigned x0 = 0u, x1 = (unsigned)i;
    threefry2x32(0u, 42u, x0, x1);
    unsigned bits = x0 ^ x1;
#else
    int half = nnz >> 1;
    int j = (i < half) ? i : i - half;
    unsigned x0 = (unsigned)j, x1 = (unsigned)(j + half);
    threefry2x32(0u, 42u, x0, x1);
    unsigned bits = (i < half) ? x0 : x1;
#endif
    float u = __uint_as_float((bits >> 9) | 0x3f800000u) - 1.0f;
    return u < 0.8f;
}

// --- item mask: mask[bat_items[n]] = 1 -------------------------------------
__global__ void k_mask(const int* __restrict__ bat_items, unsigned char* __restrict__ mask,
                       int N) {
    int t = blockIdx.x * blockDim.x + threadIdx.x;
    if (t < N) mask[bat_items[t]] = 1;
}

// --- sparse scatter: hidden[row] += 1.25 * en_emb[col]  (one wave per nnz) --
__global__ void k_scatter(const int* __restrict__ sp_row, const int* __restrict__ sp_col,
                          const float* __restrict__ en_emb, float* __restrict__ hidden,
                          int nnz) {
    int t = blockIdx.x * blockDim.x + threadIdx.x;
    int i = t >> 6;            // nnz index (wave-uniform)
    int lane = t & 63;         // feature dim
    if (i >= nnz) return;
    if (!keep_mask(i, nnz)) return;   // wave-uniform branch
    int row = sp_row[i];
    int col = sp_col[i];
    float v = 1.25f * en_emb[(size_t)col * 64 + lane];
    atomicAdd(&hidden[row * 64 + lane], v);
}

// --- hidden = tanh(hidden + user_emb[uids] + en_offset) --------------------
__global__ void k_hfinish(float* __restrict__ hidden, const float* __restrict__ user_emb,
                          const int* __restrict__ user_ids, const float* __restrict__ en_off,
                          int B) {
    int t = blockIdx.x * blockDim.x + threadIdx.x;
    if (t >= B * 64) return;
    int b = t >> 6, d = t & 63;
    int uid = user_ids[b];
    float h = hidden[t] + user_emb[(size_t)uid * 64 + d] + en_off[d];
    hidden[t] = tanhf(h);
}

// --- ratings: 16 lanes per pair, float4 loads, shfl-xor reduce -------------
__global__ void k_ratings(const float* __restrict__ hidden, const float* __restrict__ de_emb,
                          const float* __restrict__ de_bias,
                          const int* __restrict__ bat_idx, const int* __restrict__ bat_items,
                          float* __restrict__ out, int N) {
    int t = blockIdx.x * blockDim.x + threadIdx.x;
    int n = t >> 4;            // pair index (uniform across the 16-lane group)
    int l = t & 15;
    if (n >= N) return;
    int b  = bat_idx[n];
    int it = bat_items[n];
    float4 hv = *reinterpret_cast<const float4*>(hidden + (size_t)b  * 64 + l * 4);
    float4 dv = *reinterpret_cast<const float4*>(de_emb + (size_t)it * 64 + l * 4);
    float s = hv.x * dv.x + hv.y * dv.y + hv.z * dv.z + hv.w * dv.w;
    s += __shfl_xor(s, 1);
    s += __shfl_xor(s, 2);
    s += __shfl_xor(s, 4);
    s += __shfl_xor(s, 8);
    if (l == 0) out[n] = s + de_bias[it];
}

// --- reg part A: masked sum of en^2 + de^2 + de_bias^2 over items ----------
// Grid-stride: few blocks, many items each, ONE atomic per block.
__global__ void k_reg_items(const unsigned char* __restrict__ mask,
                            const float* __restrict__ en_emb, const float* __restrict__ de_emb,
                            const float* __restrict__ de_bias, float* __restrict__ reg,
                            int num_items) {
    const int work = num_items * 16;
    const int stride = gridDim.x * blockDim.x;
    float s = 0.f;
    for (int t = blockIdx.x * blockDim.x + threadIdx.x; t < work; t += stride) {
        int i = t >> 4, l = t & 15;
        if (mask[i]) {
            float4 e = *reinterpret_cast<const float4*>(en_emb + (size_t)i * 64 + l * 4);
            float4 d = *reinterpret_cast<const float4*>(de_emb + (size_t)i * 64 + l * 4);
            s += e.x*e.x + e.y*e.y + e.z*e.z + e.w*e.w
               + d.x*d.x + d.y*d.y + d.z*d.z + d.w*d.w;
            if (l == 0) { float bb = de_bias[i]; s += bb * bb; }
        }
    }
    for (int m = 1; m < 64; m <<= 1) s += __shfl_xor(s, m);
    __shared__ float wsum[4];
    if ((threadIdx.x & 63) == 0) wsum[threadIdx.x >> 6] = s;
    __syncthreads();
    if (threadIdx.x == 0)
        atomicAdd(reg, 0.5f * (wsum[0] + wsum[1] + wsum[2] + wsum[3]));
}

// --- reg part B: sum user_emb[uids]^2 (dups included) + offset^2 -----------
__global__ void k_reg_user(const float* __restrict__ user_emb, const int* __restrict__ user_ids,
                           const float* __restrict__ en_off, float* __restrict__ reg, int B) {
    const int work = B * 16;
    const int stride = gridDim.x * blockDim.x;
    float s = 0.f;
    for (int t = blockIdx.x * blockDim.x + threadIdx.x; t < work; t += stride) {
        int b = t >> 4, l = t & 15;
        int uid = user_ids[b];
        float4 u = *reinterpret_cast<const float4*>(user_emb + (size_t)uid * 64 + l * 4);
        s += u.x*u.x + u.y*u.y + u.z*u.z + u.w*u.w;
    }
    if (blockIdx.x == 0 && threadIdx.x < 64) {   // en_offset^2, 64 dims
        float o = en_off[threadIdx.x];
        s += o * o;
    }
    for (int m = 1; m < 64; m <<= 1) s += __shfl_xor(s, m);
    __shared__ float wsum[4];
    if ((threadIdx.x & 63) == 0) wsum[threadIdx.x >> 6] = s;
    __syncthreads();
    if (threadIdx.x == 0)
        atomicAdd(reg, 0.5f * (wsum[0] + wsum[1] + wsum[2] + wsum[3]));
}

extern "C" void kernel_launch(void* const* d_in, const int* in_sizes, int n_in,
                              void* d_out, int out_size, void* d_ws, size_t ws_size,
                              hipStream_t stream) {
    const int*   user_ids  = (const int*)  d_in[0];
    const int*   bat_idx   = (const int*)  d_in[1];
    const int*   sp_row    = (const int*)  d_in[2];
    const int*   sp_col    = (const int*)  d_in[3];
    const int*   bat_items = (const int*)  d_in[4];
    const float* en_emb    = (const float*)d_in[5];
    const float* en_off    = (const float*)d_in[6];
    const float* de_emb    = (const float*)d_in[7];
    const float* de_bias   = (const float*)d_in[8];
    const float* user_emb  = (const float*)d_in[9];

    const int B         = in_sizes[0];
    const int N         = in_sizes[1];
    const int NNZ       = in_sizes[2];
    const int NUM_ITEMS = in_sizes[8];

    float* out = (float*)d_out;        // ratings [N]
    float* reg = out + N;              // reg_loss scalar

    float* hidden = (float*)d_ws;                               // B*64 floats = 1 MiB
    unsigned char* mask = (unsigned char*)d_ws + (size_t)B * 64 * 4;  // NUM_ITEMS bytes

    hipMemsetAsync(hidden, 0, (size_t)B * 64 * sizeof(float), stream);
    hipMemsetAsync(mask, 0, (size_t)NUM_ITEMS, stream);
    hipMemsetAsync(reg, 0, sizeof(float), stream);

    k_mask   <<<(N + 255) / 256, 256, 0, stream>>>(bat_items, mask, N);
    k_scatter<<<(NNZ * 64 + 255) / 256, 256, 0, stream>>>(sp_row, sp_col, en_emb, hidden, NNZ);
    k_hfinish<<<(B * 64 + 255) / 256, 256, 0, stream>>>(hidden, user_emb, user_ids, en_off, B);
    k_ratings<<<(int)(((size_t)N * 16 + 255) / 256), 256, 0, stream>>>(
        hidden, de_emb, de_bias, bat_idx, bat_items, out, N);
    k_reg_items<<<256, 256, 0, stream>>>(mask, en_emb, de_emb, de_bias, reg, NUM_ITEMS);
    k_reg_user <<<64, 256, 0, stream>>>(user_emb, user_ids, en_off, reg, B);
}